// Round 3
// baseline (536.558 us; speedup 1.0000x reference)
//
#include <hip/hip_runtime.h>
#include <hip/hip_bf16.h>
#include <stdint.h>

#define NTOK 49
#define CDIM 192
#define NHEADS 6

typedef __attribute__((ext_vector_type(8))) short bf16x8;
typedef __attribute__((ext_vector_type(4))) float f32x4;

// RNE float -> bf16 (bit trick)
__device__ __forceinline__ short f2b(float f) {
    uint32_t u = __float_as_uint(f);
    uint32_t r = (u + 0x7fffu + ((u >> 16) & 1u)) >> 16;
    return (short)r;
}

// Fast pack: 8 consecutive fp32 -> bf16x8 (round-half-up via +0x8000, then v_perm)
__device__ __forceinline__ bf16x8 cvt8(const float* p) {
    f32x4 a = *(const f32x4*)p;
    f32x4 b = *(const f32x4*)(p + 4);
    union { uint32_t u[4]; bf16x8 v; } r;
    uint32_t e0 = __float_as_uint(a[0]) + 0x8000u, e1 = __float_as_uint(a[1]) + 0x8000u;
    uint32_t e2 = __float_as_uint(a[2]) + 0x8000u, e3 = __float_as_uint(a[3]) + 0x8000u;
    uint32_t e4 = __float_as_uint(b[0]) + 0x8000u, e5 = __float_as_uint(b[1]) + 0x8000u;
    uint32_t e6 = __float_as_uint(b[2]) + 0x8000u, e7 = __float_as_uint(b[3]) + 0x8000u;
    r.u[0] = __builtin_amdgcn_perm(e1, e0, 0x07060302u);
    r.u[1] = __builtin_amdgcn_perm(e3, e2, 0x07060302u);
    r.u[2] = __builtin_amdgcn_perm(e5, e4, 0x07060302u);
    r.u[3] = __builtin_amdgcn_perm(e7, e6, 0x07060302u);
    return r.v;
}

// One-shot: transpose+cast qkv_w [192][576]f32 -> wt [576][192]bf16,
//           proj_w [192][192]f32 -> pwt [192][192]bf16
__global__ void transpose_w(const float* __restrict__ qkv_w,
                            const float* __restrict__ proj_w,
                            short* __restrict__ wt, short* __restrict__ pwt) {
    int idx = blockIdx.x * 256 + threadIdx.x;
    if (idx < CDIM * 3 * CDIM) {
        int c = idx / (3 * CDIM), j = idx % (3 * CDIM);
        wt[j * CDIM + c] = f2b(qkv_w[idx]);
    }
    if (idx < CDIM * CDIM) {
        int c = idx / CDIM, j = idx % CDIM;
        pwt[j * CDIM + c] = f2b(proj_w[idx]);
    }
}

__global__ __launch_bounds__(256, 1)
void winattn_kernel(const float* __restrict__ x, const float* __restrict__ mask,
                    const short* __restrict__ wt, const float* __restrict__ qkvb,
                    const short* __restrict__ pwt, const float* __restrict__ projb,
                    float* __restrict__ out) {
    // LDS (~43 KB). Strides: 40/72 shorts -> 16B-aligned rows, <=2-way bank aliasing.
    __shared__ __align__(16) short qbuf[2][64][40];   // [head-in-pair][token][d]
    __shared__ __align__(16) short kbuf[2][64][40];   // [head-in-pair][token][d]
    __shared__ __align__(16) short vtbuf[2][32][72];  // [head-in-pair][d][token]  (V transposed)
    __shared__ __align__(16) short Pbuf[4][16][72];   // per-wave P rows (A-layout staging)
    __shared__ __align__(16) short Obuf[64][40];      // per-head attention output [token][d]

    const int b = blockIdx.x;
    const int tid = threadIdx.x;
    const int wv = tid >> 6;       // wave 0..3
    const int lane = tid & 63;
    const int q4 = lane >> 4;      // quad 0..3
    const int l16 = lane & 15;

    // ---- persistent x A-fragments: wave holds all 4 mtiles x 6 ksteps (96 VGPRs) ----
    const float* xg = x + (size_t)b * NTOK * CDIM;
    bf16x8 zero = {};
    bf16x8 afr[4][6];
#pragma unroll
    for (int mt = 0; mt < 4; mt++) {
        int n = mt * 16 + l16;
        const float* xr = xg + n * CDIM;
        bool valid = (n < NTOK);
#pragma unroll
        for (int ks = 0; ks < 6; ks++)
            afr[mt][ks] = valid ? cvt8(xr + ks * 32 + q4 * 8) : zero;
    }

    // ---- premask: mask value (+ -inf for pad rows/cols), rows = wv*16 + q4*4 + r ----
    const float* mg = mask + (size_t)(b & 63) * NTOK * NTOK;
    float premask[4][4];
#pragma unroll
    for (int ct = 0; ct < 4; ct++)
#pragma unroll
        for (int r = 0; r < 4; r++) {
            int row = wv * 16 + q4 * 4 + r;
            int col = ct * 16 + l16;
            float mv = mg[min(row, 48) * NTOK + min(col, 48)];
            premask[ct][r] = (row < NTOK && col < NTOK) ? mv : -1e30f;
        }

    // ---- persistent proj accumulators: wave owns 3 col-tiles x 4 mtiles ----
    f32x4 acco[3][4];
#pragma unroll
    for (int a = 0; a < 3; a++)
#pragma unroll
        for (int m = 0; m < 4; m++) acco[a][m] = (f32x4){0.f, 0.f, 0.f, 0.f};

    const float SCALE = 0.17677669529663687f;

    for (int p = 0; p < 3; p++) {            // head pairs (2p, 2p+1)
        __syncthreads();                     // q/k/vt overwrite vs prior reads

        // ================= QKV for this head pair =================
#pragma unroll
        for (int t = 0; t < 3; t++) {
            int i = wv * 3 + t;              // 12 jtiles / 4 waves
            int jt;
            if (i < 4)      jt = 4 * p + i;            // q cols
            else if (i < 8) jt = 12 + 4 * p + (i - 4); // k cols
            else            jt = 24 + 4 * p + (i - 8); // v cols
            int jb = jt * 16;
            const short* wrow = wt + (size_t)(jb + l16) * CDIM;
            bf16x8 bfr[6];
#pragma unroll
            for (int ks = 0; ks < 6; ks++)
                bfr[ks] = *(const bf16x8*)(wrow + ks * 32 + q4 * 8);
            f32x4 acc[4];
#pragma unroll
            for (int m = 0; m < 4; m++) acc[m] = (f32x4){0.f, 0.f, 0.f, 0.f};
#pragma unroll
            for (int ks = 0; ks < 6; ks++)
#pragma unroll
                for (int mt = 0; mt < 4; mt++)
                    acc[mt] = __builtin_amdgcn_mfma_f32_16x16x32_bf16(afr[mt][ks], bfr[ks], acc[mt], 0, 0, 0);
            float bias = qkvb[jb + l16];
            int sect = jb / CDIM;            // 0=q 1=k 2=v
            int jm = jb % CDIM;
            int hl = (jm / 32) - 2 * p;      // head within pair
            int d = (jm % 32) + l16;
#pragma unroll
            for (int mt = 0; mt < 4; mt++)
#pragma unroll
                for (int r = 0; r < 4; r++) {
                    int row = mt * 16 + q4 * 4 + r;
                    short v = f2b(acc[mt][r] + bias);
                    if (sect == 0)      qbuf[hl][row][d] = v;
                    else if (sect == 1) kbuf[hl][row][d] = v;
                    else                vtbuf[hl][d][row] = v;
                }
        }
        __syncthreads();

        // ================= attention + proj per head =================
#pragma unroll
        for (int hl = 0; hl < 2; hl++) {
            int h = 2 * p + hl;
            // ---- S = Q K^T (wave handles row-tile wv; K=32 in one MFMA) ----
            f32x4 accs[4];
#pragma unroll
            for (int c = 0; c < 4; c++) accs[c] = (f32x4){0.f, 0.f, 0.f, 0.f};
            bf16x8 qa = *(const bf16x8*)&qbuf[hl][wv * 16 + l16][q4 * 8];
#pragma unroll
            for (int ct = 0; ct < 4; ct++) {
                bf16x8 kb = *(const bf16x8*)&kbuf[hl][ct * 16 + l16][q4 * 8];
                accs[ct] = __builtin_amdgcn_mfma_f32_16x16x32_bf16(qa, kb, accs[ct], 0, 0, 0);
            }
            // ---- softmax across 64 cols: in-lane over 4 ct + 16-lane xor shuffle ----
            float s[4][4], mx[4], lsum[4];
#pragma unroll
            for (int r = 0; r < 4; r++) {
                mx[r] = -3.4e38f;
#pragma unroll
                for (int ct = 0; ct < 4; ct++) {
                    s[ct][r] = accs[ct][r] * SCALE + premask[ct][r];
                    mx[r] = fmaxf(mx[r], s[ct][r]);
                }
            }
#pragma unroll
            for (int w2 = 1; w2 < 16; w2 <<= 1)
#pragma unroll
                for (int r = 0; r < 4; r++) mx[r] = fmaxf(mx[r], __shfl_xor(mx[r], w2));
#pragma unroll
            for (int r = 0; r < 4; r++) lsum[r] = 0.f;
#pragma unroll
            for (int ct = 0; ct < 4; ct++)
#pragma unroll
                for (int r = 0; r < 4; r++) {
                    float e = __expf(s[ct][r] - mx[r]);
                    s[ct][r] = e;
                    lsum[r] += e;
                }
#pragma unroll
            for (int w2 = 1; w2 < 16; w2 <<= 1)
#pragma unroll
                for (int r = 0; r < 4; r++) lsum[r] += __shfl_xor(lsum[r], w2);
            // ---- P -> LDS (C-layout -> A-layout round-trip), unnormalized ----
#pragma unroll
            for (int ct = 0; ct < 4; ct++)
#pragma unroll
                for (int r = 0; r < 4; r++)
                    Pbuf[wv][q4 * 4 + r][ct * 16 + l16] = f2b(s[ct][r]);
            // ---- O = P V (wave's own P rows; V^T gives contiguous b-frags) ----
            f32x4 accp[2];
            accp[0] = (f32x4){0.f, 0.f, 0.f, 0.f};
            accp[1] = (f32x4){0.f, 0.f, 0.f, 0.f};
#pragma unroll
            for (int ks = 0; ks < 2; ks++) {
                bf16x8 pa = *(const bf16x8*)&Pbuf[wv][l16][ks * 32 + q4 * 8];
#pragma unroll
                for (int jt = 0; jt < 2; jt++) {
                    bf16x8 vb = *(const bf16x8*)&vtbuf[hl][jt * 16 + l16][ks * 32 + q4 * 8];
                    accp[jt] = __builtin_amdgcn_mfma_f32_16x16x32_bf16(pa, vb, accp[jt], 0, 0, 0);
                }
            }
            __syncthreads();   // prior proj reads of Obuf are done
            float rl[4];
#pragma unroll
            for (int r = 0; r < 4; r++) rl[r] = 1.0f / lsum[r];
#pragma unroll
            for (int jt = 0; jt < 2; jt++)
#pragma unroll
                for (int r = 0; r < 4; r++)
                    Obuf[wv * 16 + q4 * 4 + r][jt * 16 + l16] = f2b(accp[jt][r] * rl[r]);
            __syncthreads();
            // ---- proj: accumulate K=32 slice of this head into persistent acco ----
#pragma unroll
            for (int jtl = 0; jtl < 3; jtl++) {
                int jb = (wv * 3 + jtl) * 16;
                bf16x8 pb = *(const bf16x8*)(pwt + (size_t)(jb + l16) * CDIM + h * 32 + q4 * 8);
#pragma unroll
                for (int mt = 0; mt < 4; mt++) {
                    bf16x8 oa = *(const bf16x8*)&Obuf[mt * 16 + l16][q4 * 8];
                    acco[jtl][mt] = __builtin_amdgcn_mfma_f32_16x16x32_bf16(oa, pb, acco[jtl][mt], 0, 0, 0);
                }
            }
        }
    }

    // ---- epilogue: + proj bias, store FP32 ----
#pragma unroll
    for (int jtl = 0; jtl < 3; jtl++) {
        int jb = (wv * 3 + jtl) * 16;
        float bias = projb[jb + l16];
#pragma unroll
        for (int mt = 0; mt < 4; mt++)
#pragma unroll
            for (int r = 0; r < 4; r++) {
                int n = mt * 16 + q4 * 4 + r;
                if (n < NTOK)
                    out[((size_t)b * NTOK + n) * CDIM + jb + l16] = acco[jtl][mt][r] + bias;
            }
    }
}

extern "C" void kernel_launch(void* const* d_in, const int* in_sizes, int n_in,
                              void* d_out, int out_size, void* d_ws, size_t ws_size,
                              hipStream_t stream) {
    const float* x      = (const float*)d_in[0];
    const float* mask   = (const float*)d_in[1];
    const float* qkv_w  = (const float*)d_in[2];
    const float* qkv_b  = (const float*)d_in[3];
    const float* proj_w = (const float*)d_in[4];
    const float* proj_b = (const float*)d_in[5];
    short* wt  = (short*)d_ws;                 // [576][192] bf16
    short* pwt = wt + CDIM * 3 * CDIM;         // [192][192] bf16
    float* out = (float*)d_out;
    int B = in_sizes[0] / (NTOK * CDIM);       // 4096

    transpose_w<<<(CDIM * 3 * CDIM + 255) / 256, 256, 0, stream>>>(qkv_w, proj_w, wt, pwt);
    winattn_kernel<<<B, 256, 0, stream>>>(x, mask, wt, qkv_b, pwt, proj_b, out);
}